// Round 10
// baseline (218.427 us; speedup 1.0000x reference)
//
#include <hip/hip_runtime.h>
#include <cstddef>
#include <cstdint>

// B=8192, T=512, I=4, H=32, O=4 — 2-layer tanh RNN + linear head, fp32 I/O.
constexpr int kB = 8192, kT = 512, kI = 4, kH = 32, kO = 4;

typedef _Float16 f16x8 __attribute__((ext_vector_type(8)));
typedef float    f32x4 __attribute__((ext_vector_type(4)));

#define MFMA(a, b, c) __builtin_amdgcn_mfma_f32_16x16x32_f16((a), (b), (c), 0, 0, 0)

// Barrier waiting on LDS ops only (global loads/stores stay in flight).
__device__ __forceinline__ void bar_lds() {
    asm volatile("s_waitcnt lgkmcnt(0)" ::: "memory");
    __builtin_amdgcn_s_barrier();
    __builtin_amdgcn_sched_barrier(0);
}

// Rational tanh: Pade[5/4] from the continued fraction
//   tanh x = x/(1+u/(3+u/(5+u/(7+u/9)))),  u = x^2
//          = x*(945 + 105u + u^2) / (945 + 420u + 15u^2)
// Clamped to |x|<=3.5. Max abs err ~1.3e-3 (at/beyond clamp), ~1e-5 for |x|<2.
// One trans op (rcp) instead of two (exp2+rcp) -> shorter dependency chain.
__device__ __forceinline__ float rtanh(float x) {
    float xc = fminf(fmaxf(x, -3.5f), 3.5f);
    float u  = xc * xc;
    float n  = fmaf(u, u + 105.0f, 945.0f);
    float d  = fmaf(u, fmaf(u, 15.0f, 420.0f), 945.0f);
    return (xc * n) * __builtin_amdgcn_rcpf(d);
}

__device__ __forceinline__ f32x4 tanh4(f32x4 a) {
    f32x4 t;
#pragma unroll
    for (int r = 0; r < 4; ++r) t[r] = rtanh(a[r]);
    return t;
}

__device__ __forceinline__ float4 ld4(const float* p) { return *(const float4*)p; }

// A/B fragment from two float4s: elems 0-3 = k {4g..4g+3}, 4-7 = k {16+4g..}.
__device__ __forceinline__ f16x8 pack_frag(float4 lo, float4 hi) {
    f16x8 r;
    r[0] = (_Float16)lo.x; r[1] = (_Float16)lo.y;
    r[2] = (_Float16)lo.z; r[3] = (_Float16)lo.w;
    r[4] = (_Float16)hi.x; r[5] = (_Float16)hi.y;
    r[6] = (_Float16)hi.z; r[7] = (_Float16)hi.w;
    return r;
}

// D-tile regs -> next-step B k-slots; pure per-lane (4x v_cvt_pkrtz).
__device__ __forceinline__ f16x8 pack_state(f32x4 a, f32x4 b) {
    union { f16x8 v; uint32_t u[4]; } r;
    r.u[0] = __builtin_bit_cast(uint32_t, __builtin_amdgcn_cvt_pkrtz(a[0], a[1]));
    r.u[1] = __builtin_bit_cast(uint32_t, __builtin_amdgcn_cvt_pkrtz(a[2], a[3]));
    r.u[2] = __builtin_bit_cast(uint32_t, __builtin_amdgcn_cvt_pkrtz(b[0], b[1]));
    r.u[3] = __builtin_bit_cast(uint32_t, __builtin_amdgcn_cvt_pkrtz(b[2], b[3]));
    return r.v;
}

// Role-pipelined 4-wave structure, one 16-batch tile per block:
//   wave0 A: full L0 — h0 recurrence ENTIRELY in registers (no exchange on the
//            serial path); consumes xc[] from C via LDS ring (read 1 phase early)
//   wave1 B: full L1 — h1 in registers; consumes h0 with 3-phase lag
//   wave2 C: xc[t] = W_ih0 x_t + b0 producer (feed-forward, runs ahead)
//   wave3 D: head + store, 6-phase lag
// Phase p: C->xc[p]; A->h0[p-2]; B->h1[p-4]; D->out[p-6]. All ds_reads are
// issued one phase before use (~400 cy slack). One lgkm-only barrier per phase.
// 512 blocks -> 2 blocks/CU -> 2 waves/SIMD (the regime R8 proved good).
__global__ __launch_bounds__(256, 2) void rnn2_pipe(
    const float* __restrict__ X,
    const float* __restrict__ W_ih0, const float* __restrict__ W_hh0,
    const float* __restrict__ b_ih0, const float* __restrict__ b_hh0,
    const float* __restrict__ W_ih1, const float* __restrict__ W_hh1,
    const float* __restrict__ b_ih1, const float* __restrict__ b_hh1,
    const float* __restrict__ W_ll, const float* __restrict__ b_ll,
    float* __restrict__ out)
{
    const int  tid = threadIdx.x;
    const int  wid = tid >> 6;       // 0=A(L0) 1=B(L1) 2=C(xc) 3=D(head)
    const int  l   = tid & 63;
    const int  c   = l & 15;         // batch col within tile / A row m
    const int  g   = l >> 4;         // k-group
    const bool g0  = (g == 0);
    const int  b   = blockIdx.x * 16 + c;
    const int  k0  = 4 * g;

    __shared__ f32x4 xcring[4][2][64];  // xc[t] in D layout (fp32, exact)
    __shared__ uint4 h0ring[4][64];     // h0[t] as packed B-fragments
    __shared__ uint4 h1ring[4][64];     // h1[t] as packed B-fragments

    const float4 z4 = make_float4(0.f, 0.f, 0.f, 0.f);
    const f32x4  zf = {0.f, 0.f, 0.f, 0.f};
    union { f16x8 v; uint32_t u[4]; } zz;
    zz.u[0] = zz.u[1] = zz.u[2] = zz.u[3] = 0u;

    // ---- per-role loop-invariant weights/biases ----
    f16x8 Wt0 = zz.v, Wt1 = zz.v, Wt2 = zz.v, Wt3 = zz.v, Wt4 = zz.v;
    f32x4 bs0 = zf, bs1 = zf;
    const float* wp;
    if (wid == 0) {          // A: W_hh0 row-tiles
        wp = W_hh0 + c * kH;        Wt0 = pack_frag(ld4(wp + k0), ld4(wp + 16 + k0));
        wp = W_hh0 + (c + 16) * kH; Wt1 = pack_frag(ld4(wp + k0), ld4(wp + 16 + k0));
    } else if (wid == 1) {   // B: W_ih1, W_hh1 row-tiles + bias1
        wp = W_ih1 + c * kH;        Wt0 = pack_frag(ld4(wp + k0), ld4(wp + 16 + k0));
        wp = W_ih1 + (c + 16) * kH; Wt1 = pack_frag(ld4(wp + k0), ld4(wp + 16 + k0));
        wp = W_hh1 + c * kH;        Wt2 = pack_frag(ld4(wp + k0), ld4(wp + 16 + k0));
        wp = W_hh1 + (c + 16) * kH; Wt3 = pack_frag(ld4(wp + k0), ld4(wp + 16 + k0));
#pragma unroll
        for (int r = 0; r < 4; ++r) {
            bs0[r] = b_ih1[k0 + r]      + b_hh1[k0 + r];
            bs1[r] = b_ih1[16 + k0 + r] + b_hh1[16 + k0 + r];
        }
    } else if (wid == 2) {   // C: W_ih0 (k<4 live) + bias0
        Wt0 = pack_frag(g0 ? ld4(W_ih0 + c * kI) : z4, z4);
        Wt1 = pack_frag(g0 ? ld4(W_ih0 + (c + 16) * kI) : z4, z4);
#pragma unroll
        for (int r = 0; r < 4; ++r) {
            bs0[r] = b_ih0[k0 + r]      + b_hh0[k0 + r];
            bs1[r] = b_ih0[16 + k0 + r] + b_hh0[16 + k0 + r];
        }
    } else {                 // D: W_ll (rows >=4 zero) + b_ll
        Wt4 = (c < kO)
            ? pack_frag(ld4(W_ll + c * kH + k0), ld4(W_ll + c * kH + 16 + k0))
            : pack_frag(z4, z4);
#pragma unroll
        for (int r = 0; r < 4; ++r) bs0[r] = g0 ? b_ll[r] : 0.f;
    }

    // ---- per-role persistent state ----
    f16x8 Bh0 = zz.v;                 // A: h0[s-1] (in-register recurrence)
    f16x8 Bh1 = zz.v;                 // B: h1[s-1]
    f16x8 h0cur = zz.v, h1cur = zz.v; // B/D: staged ring reads
    f32x4 xc0 = zf, xc1 = zf;         // A: xc[s] staged
    const float* xp = X   + (size_t)b * (kT * kI);
    float*       op = out + (size_t)b * (kT * kO);
    float4 xv0, xv1;                  // C: x[p], x[p+1] (2-phase prefetch)
    union { f16x8 v; uint32_t u[4]; } bx; bx.u[0]=bx.u[1]=bx.u[2]=bx.u[3]=0u;
    if (wid == 2) { xv0 = ld4(xp); xv1 = ld4(xp + kI); }

    for (int p = 0; p < kT + 6; ++p) {
        if (wid == 0) {
            // ================= A: h0[p-2] =================
            f32x4 nx0, nx1;
            const bool rd = (p >= 1) & (p <= kT);
            const bool go = (p >= 2) & (p <= kT + 1);
            if (rd) {   // stage xc[p-1] (consumed next phase -> latency hidden)
                nx0 = xcring[(p - 1) & 3][0][l];
                nx1 = xcring[(p - 1) & 3][1][l];
            }
            if (go) {
                __builtin_amdgcn_s_setprio(1);
                f32x4 a0 = MFMA(Wt0, Bh0, xc0);
                f32x4 a1 = MFMA(Wt1, Bh0, xc1);
                __builtin_amdgcn_s_setprio(0);
                Bh0 = pack_state(tanh4(a0), tanh4(a1));
                h0ring[(p - 2) & 3][l] = __builtin_bit_cast(uint4, Bh0);
            }
            xc0 = nx0; xc1 = nx1;
        } else if (wid == 1) {
            // ================= B: h1[p-4] =================
            f16x8 nh0;
            const bool rd = (p >= 3) & (p <= kT + 2);
            const bool go = (p >= 4) & (p <= kT + 3);
            if (rd) nh0 = __builtin_bit_cast(f16x8, h0ring[(p - 3) & 3][l]);
            if (go) {
                __builtin_amdgcn_s_setprio(1);
                f32x4 p0 = MFMA(Wt0, h0cur, bs0);
                f32x4 p1 = MFMA(Wt1, h0cur, bs1);
                f32x4 q0 = MFMA(Wt2, Bh1, zf);
                f32x4 q1 = MFMA(Wt3, Bh1, zf);
                __builtin_amdgcn_s_setprio(0);
                Bh1 = pack_state(tanh4(p0 + q0), tanh4(p1 + q1));
                h1ring[(p - 4) & 3][l] = __builtin_bit_cast(uint4, Bh1);
            }
            h0cur = nh0;
        } else if (wid == 2) {
            // ================= C: xc[p] =================
            if (p < kT) {
                const int idx = (p + 2 < kT) ? (p + 2) : (kT - 1);
                float4 xn = ld4(xp + idx * kI);          // 2-phase prefetch
                bx.u[0] = __builtin_bit_cast(uint32_t, __builtin_amdgcn_cvt_pkrtz(xv0.x, xv0.y));
                bx.u[1] = __builtin_bit_cast(uint32_t, __builtin_amdgcn_cvt_pkrtz(xv0.z, xv0.w));
                // k>=4 slots of bx multiply against zeroed A slots -> no mask needed
                f32x4 c0 = MFMA(Wt0, bx.v, bs0);
                f32x4 c1 = MFMA(Wt1, bx.v, bs1);
                xcring[p & 3][0][l] = c0;
                xcring[p & 3][1][l] = c1;
                xv0 = xv1; xv1 = xn;
            }
        } else {
            // ================= D: head + store out[p-6] =================
            f16x8 nh1;
            const bool rd = (p >= 5) & (p <= kT + 4);
            const bool go = (p >= 6);
            if (rd) nh1 = __builtin_bit_cast(f16x8, h1ring[(p - 5) & 3][l]);
            if (go) {
                f32x4 o = MFMA(Wt4, h1cur, bs0);
                if (g0) *(float4*)(op + (size_t)(p - 6) * kO) =
                    make_float4(o[0], o[1], o[2], o[3]);
            }
            h1cur = nh1;
        }
        bar_lds();
    }
}

extern "C" void kernel_launch(void* const* d_in, const int* in_sizes, int n_in,
                              void* d_out, int out_size, void* d_ws, size_t ws_size,
                              hipStream_t stream) {
    const float* X     = (const float*)d_in[0];
    const float* W_ih0 = (const float*)d_in[1];
    const float* W_hh0 = (const float*)d_in[2];
    const float* b_ih0 = (const float*)d_in[3];
    const float* b_hh0 = (const float*)d_in[4];
    const float* W_ih1 = (const float*)d_in[5];
    const float* W_hh1 = (const float*)d_in[6];
    const float* b_ih1 = (const float*)d_in[7];
    const float* b_hh1 = (const float*)d_in[8];
    const float* W_ll  = (const float*)d_in[9];
    const float* b_ll  = (const float*)d_in[10];
    float* out = (float*)d_out;

    rnn2_pipe<<<dim3(kB / 16), dim3(256), 0, stream>>>(
        X, W_ih0, W_hh0, b_ih0, b_hh0, W_ih1, W_hh1, b_ih1, b_hh1, W_ll, b_ll, out);
}

// Round 11
// 167.858 us; speedup vs baseline: 1.3013x; 1.3013x over previous
//
#include <hip/hip_runtime.h>
#include <cstddef>
#include <cstdint>

// B=8192, T=512, I=4, H=32, O=4 — 2-layer tanh RNN + linear head, fp32 I/O.
constexpr int kB = 8192, kT = 512, kI = 4, kH = 32, kO = 4;

typedef _Float16 f16x8 __attribute__((ext_vector_type(8)));
typedef float    f32x4 __attribute__((ext_vector_type(4)));

#define MFMA(a, b, c) __builtin_amdgcn_mfma_f32_16x16x32_f16((a), (b), (c), 0, 0, 0)

// Barrier waiting on LDS ops only (global loads/stores stay in flight).
__device__ __forceinline__ void bar_lds() {
    asm volatile("s_waitcnt lgkmcnt(0)" ::: "memory");
    __builtin_amdgcn_s_barrier();
    __builtin_amdgcn_sched_barrier(0);
}

__device__ __forceinline__ float fast_tanh(float x) {
    // tanh(x) = 1 - 2/(e^{2x}+1); exp2-based, saturates correctly, rel err ~1e-6
    float e = __builtin_amdgcn_exp2f(x * 2.8853900817779268f);
    return 1.0f - 2.0f * __builtin_amdgcn_rcpf(e + 1.0f);
}

__device__ __forceinline__ float4 ld4(const float* p) { return *(const float4*)p; }

// A/B fragment from two float4s: elems 0-3 = k {4g..4g+3}, 4-7 = k {16+4g..}.
__device__ __forceinline__ f16x8 pack_frag(float4 lo, float4 hi) {
    f16x8 r;
    r[0] = (_Float16)lo.x; r[1] = (_Float16)lo.y;
    r[2] = (_Float16)lo.z; r[3] = (_Float16)lo.w;
    r[4] = (_Float16)hi.x; r[5] = (_Float16)hi.y;
    r[6] = (_Float16)hi.z; r[7] = (_Float16)hi.w;
    return r;
}

// D-tile regs -> next-step B k-slots; pure per-lane (4x v_cvt_pkrtz).
__device__ __forceinline__ f16x8 pack_state(f32x4 a, f32x4 b) {
    union { f16x8 v; uint32_t u[4]; } r;
    r.u[0] = __builtin_bit_cast(uint32_t, __builtin_amdgcn_cvt_pkrtz(a[0], a[1]));
    r.u[1] = __builtin_bit_cast(uint32_t, __builtin_amdgcn_cvt_pkrtz(a[2], a[3]));
    r.u[2] = __builtin_bit_cast(uint32_t, __builtin_amdgcn_cvt_pkrtz(b[0], b[1]));
    r.u[3] = __builtin_bit_cast(uint32_t, __builtin_amdgcn_cvt_pkrtz(b[2], b[3]));
    return r.v;
}

// x[t] as B-fragment (k=0..3 live on lane-group 0 only).
__device__ __forceinline__ f16x8 bxpack(float4 xn, bool g0) {
    union { f16x8 v; uint32_t u[4]; } bx;
    bx.u[0] = g0 ? __builtin_bit_cast(uint32_t, __builtin_amdgcn_cvt_pkrtz(xn.x, xn.y)) : 0u;
    bx.u[1] = g0 ? __builtin_bit_cast(uint32_t, __builtin_amdgcn_cvt_pkrtz(xn.z, xn.w)) : 0u;
    bx.u[2] = 0u; bx.u[3] = 0u;
    return bx.v;
}

// Epoch-ring producer/consumer, one 16-batch tile per 2-wave block:
//   wave A: full layer 0 — h0 recurrence ENTIRELY in registers; publishes
//           h0[i] to a 16-slot LDS ring (off the serial path).
//   wave B: full layer 1 + head — h1 in registers; lags A by one epoch
//           (8 steps), consumes ring slots written in the previous epoch.
// ONE lgkm-only barrier per 8 steps (amortized ~20 cy/step vs ~300+ for
// per-step barriers in R6-R10). Race-free: A's epoch-e slots ((e&1)*8..+7)
// are disjoint from B's epoch-e reads (other parity); slot reuse is
// separated by two barriers. x prefetch has 8-step (~1800 cy) slack.
__global__ __launch_bounds__(128, 1) void rnn2_ring(
    const float* __restrict__ X,
    const float* __restrict__ W_ih0, const float* __restrict__ W_hh0,
    const float* __restrict__ b_ih0, const float* __restrict__ b_hh0,
    const float* __restrict__ W_ih1, const float* __restrict__ W_hh1,
    const float* __restrict__ b_ih1, const float* __restrict__ b_hh1,
    const float* __restrict__ W_ll, const float* __restrict__ b_ll,
    float* __restrict__ out)
{
    const int  tid = threadIdx.x;
    const int  wid = tid >> 6;       // 0 = A (L0), 1 = B (L1+head)
    const int  l   = tid & 63;
    const int  c   = l & 15;         // batch col within tile / A row m
    const int  g   = l >> 4;         // k-group
    const bool g0  = (g == 0);
    const int  b   = blockIdx.x * 16 + c;
    const int  k0  = 4 * g;

    __shared__ uint4 ring[16][64];   // h0 B-fragments, 2 epochs deep

    const float4 z4 = make_float4(0.f, 0.f, 0.f, 0.f);
    union { f16x8 v; uint32_t u[4]; } zz;
    zz.u[0] = zz.u[1] = zz.u[2] = zz.u[3] = 0u;

    constexpr int EP = 8;            // steps per epoch
    constexpr int NE = kT / EP;      // 64 epochs of real A work

    if (wid == 0) {
        // ================= A: layer 0, h0 in registers =================
        const float* wp = W_hh0 + c * kH;
        const f16x8 Ahh0 = pack_frag(ld4(wp + k0), ld4(wp + 16 + k0));
        wp = W_hh0 + (c + 16) * kH;
        const f16x8 Ahh1 = pack_frag(ld4(wp + k0), ld4(wp + 16 + k0));
        const f16x8 Aih0 = pack_frag(g0 ? ld4(W_ih0 + c * kI) : z4, z4);
        const f16x8 Aih1 = pack_frag(g0 ? ld4(W_ih0 + (c + 16) * kI) : z4, z4);
        f32x4 bias0, bias1;
#pragma unroll
        for (int r = 0; r < 4; ++r) {
            bias0[r] = b_ih0[k0 + r]      + b_hh0[k0 + r];
            bias1[r] = b_ih0[16 + k0 + r] + b_hh0[16 + k0 + r];
        }

        const float* xp = X + (size_t)b * (kT * kI);
        f16x8 Bh0 = zz.v;
        f32x4 xc0, xc1;              // xc[i] = W_ih0 x_i + b0

        // prologue: xc[0] from x[0]; xbuf = x[1..8]
        float4 xbuf[EP];
#pragma unroll
        for (int u = 0; u < EP; ++u) xbuf[u] = ld4(xp + (1 + u) * kI);
        {
            float4 x0 = ld4(xp);
            f16x8 bx = bxpack(x0, g0);
            xc0 = MFMA(Aih0, bx, bias0);
            xc1 = MFMA(Aih1, bx, bias1);
        }

        for (int e = 0; e < NE + 1; ++e) {
            if (e < NE) {
                // issue next epoch's x loads (8-step slack)
                float4 xn[EP];
#pragma unroll
                for (int u = 0; u < EP; ++u) {
                    int idx = EP * (e + 1) + 1 + u;
                    idx = idx < kT ? idx : (kT - 1);
                    xn[u] = ld4(xp + idx * kI);
                }
                const int sb = (e & 1) * EP;   // this epoch's slot base
#pragma unroll
                for (int u = 0; u < EP; ++u) {
                    // step i = EP*e+u: h0[i] = tanh(W_hh0 h0[i-1] + xc[i])
                    f16x8 bx = bxpack(xbuf[u], g0);
                    f32x4 a0 = MFMA(Ahh0, Bh0, xc0);
                    f32x4 a1 = MFMA(Ahh1, Bh0, xc1);
                    xc0 = MFMA(Aih0, bx, bias0);   // xc[i+1], off-chain
                    xc1 = MFMA(Aih1, bx, bias1);
                    f32x4 t0, t1;
#pragma unroll
                    for (int r = 0; r < 4; ++r) { t0[r] = fast_tanh(a0[r]); t1[r] = fast_tanh(a1[r]); }
                    Bh0 = pack_state(t0, t1);
                    ring[sb + u][l] = __builtin_bit_cast(uint4, Bh0);
                }
#pragma unroll
                for (int u = 0; u < EP; ++u) xbuf[u] = xn[u];
            }
            bar_lds();
        }
    } else {
        // ================= B: layer 1 + head, h1 in registers =================
        const float* wp = W_ih1 + c * kH;
        const f16x8 Bih0 = pack_frag(ld4(wp + k0), ld4(wp + 16 + k0));
        wp = W_ih1 + (c + 16) * kH;
        const f16x8 Bih1 = pack_frag(ld4(wp + k0), ld4(wp + 16 + k0));
        wp = W_hh1 + c * kH;
        const f16x8 Bhh0 = pack_frag(ld4(wp + k0), ld4(wp + 16 + k0));
        wp = W_hh1 + (c + 16) * kH;
        const f16x8 Bhh1 = pack_frag(ld4(wp + k0), ld4(wp + 16 + k0));
        const f16x8 All = (c < kO)
            ? pack_frag(ld4(W_ll + c * kH + k0), ld4(W_ll + c * kH + 16 + k0))
            : pack_frag(z4, z4);

        f32x4 bias1_0, bias1_1, biasll;
#pragma unroll
        for (int r = 0; r < 4; ++r) {
            bias1_0[r] = b_ih1[k0 + r]      + b_hh1[k0 + r];
            bias1_1[r] = b_ih1[16 + k0 + r] + b_hh1[16 + k0 + r];
            biasll[r]  = g0 ? b_ll[r] : 0.f;
        }

        f16x8 Bh1 = zz.v;
        float* op = out + (size_t)b * (kT * kO);

        for (int e = 0; e < NE + 1; ++e) {
            if (e >= 1) {
                const int sb = ((e - 1) & 1) * EP;   // prev epoch's slots
                const int j0 = EP * (e - 1);
#pragma unroll
                for (int u = 0; u < EP; ++u) {
                    // step j = j0+u: h1[j] = tanh(W_ih1 h0[j] + W_hh1 h1[j-1] + b1)
                    f16x8 h0 = __builtin_bit_cast(f16x8, ring[sb + u][l]);
                    f32x4 c0 = MFMA(Bih0, h0, bias1_0);
                    f32x4 c1 = MFMA(Bih1, h0, bias1_1);
                    c0 = MFMA(Bhh0, Bh1, c0);
                    c1 = MFMA(Bhh1, Bh1, c1);
                    f32x4 t0, t1;
#pragma unroll
                    for (int r = 0; r < 4; ++r) { t0[r] = fast_tanh(c0[r]); t1[r] = fast_tanh(c1[r]); }
                    Bh1 = pack_state(t0, t1);
                    // head: out[j] = W_ll h1[j] + b_ll (off the recurrence path)
                    f32x4 o = MFMA(All, Bh1, biasll);
                    if (g0) *(float4*)(op + (size_t)(j0 + u) * kO) =
                        make_float4(o[0], o[1], o[2], o[3]);
                }
            }
            bar_lds();
        }
    }
}

extern "C" void kernel_launch(void* const* d_in, const int* in_sizes, int n_in,
                              void* d_out, int out_size, void* d_ws, size_t ws_size,
                              hipStream_t stream) {
    const float* X     = (const float*)d_in[0];
    const float* W_ih0 = (const float*)d_in[1];
    const float* W_hh0 = (const float*)d_in[2];
    const float* b_ih0 = (const float*)d_in[3];
    const float* b_hh0 = (const float*)d_in[4];
    const float* W_ih1 = (const float*)d_in[5];
    const float* W_hh1 = (const float*)d_in[6];
    const float* b_ih1 = (const float*)d_in[7];
    const float* b_hh1 = (const float*)d_in[8];
    const float* W_ll  = (const float*)d_in[9];
    const float* b_ll  = (const float*)d_in[10];
    float* out = (float*)d_out;

    rnn2_ring<<<dim3(kB / 16), dim3(128), 0, stream>>>(
        X, W_ih0, W_hh0, b_ih0, b_hh0, W_ih1, W_hh1, b_ih1, b_hh1, W_ll, b_ll, out);
}

// Round 12
// 139.298 us; speedup vs baseline: 1.5681x; 1.2050x over previous
//
#include <hip/hip_runtime.h>
#include <cstddef>
#include <cstdint>

// B=8192, T=512, I=4, H=32, O=4 — 2-layer tanh RNN + linear head, fp32 I/O.
constexpr int kB = 8192, kT = 512, kI = 4, kH = 32, kO = 4;

typedef _Float16 f16x8 __attribute__((ext_vector_type(8)));
typedef float    f32x4 __attribute__((ext_vector_type(4)));

#define MFMA(a, b, c) __builtin_amdgcn_mfma_f32_16x16x32_f16((a), (b), (c), 0, 0, 0)

// Barrier waiting on LDS ops only (global loads/stores stay in flight).
__device__ __forceinline__ void bar_lds() {
    asm volatile("s_waitcnt lgkmcnt(0)" ::: "memory");
    __builtin_amdgcn_s_barrier();
    __builtin_amdgcn_sched_barrier(0);
}

// Rational tanh, Pade[5/4] of the continued fraction:
//   tanh x ~= x*(945 + 105u + u^2) / (945 + 420u + 15u^2),  u = x^2, |x|<=3.5
// ONE trans op (rcp) vs two (exp2+rcp) -> ~30 cy shorter dependency chain.
// err: ~2e-5 @|x|<=2.2 (6-sigma of this net's pre-activations), 8.8e-4 @3.5,
// <=1.8e-3 saturated. Feeds a contractive recurrence -> output err ~5e-3.
__device__ __forceinline__ float rtanh(float x) {
    float xc = fminf(fmaxf(x, -3.5f), 3.5f);
    float u  = xc * xc;
    float n  = fmaf(u, u + 105.0f, 945.0f);
    float d  = fmaf(u, fmaf(u, 15.0f, 420.0f), 945.0f);
    return (xc * n) * __builtin_amdgcn_rcpf(d);
}

__device__ __forceinline__ f32x4 tanh4(f32x4 a) {
    f32x4 t;
#pragma unroll
    for (int r = 0; r < 4; ++r) t[r] = rtanh(a[r]);
    return t;
}

__device__ __forceinline__ float4 ld4(const float* p) { return *(const float4*)p; }

// A/B fragment from two float4s: elems 0-3 = k {4g..4g+3}, 4-7 = k {16+4g..}.
__device__ __forceinline__ f16x8 pack_frag(float4 lo, float4 hi) {
    f16x8 r;
    r[0] = (_Float16)lo.x; r[1] = (_Float16)lo.y;
    r[2] = (_Float16)lo.z; r[3] = (_Float16)lo.w;
    r[4] = (_Float16)hi.x; r[5] = (_Float16)hi.y;
    r[6] = (_Float16)hi.z; r[7] = (_Float16)hi.w;
    return r;
}

// Assemble a B-operand fragment from two uint2 halves (k 0-15 | k 16-31).
__device__ __forceinline__ f16x8 asm_frag(uint2 lo, uint2 hi) {
    union { f16x8 v; uint2 p[2]; } r;
    r.p[0] = lo; r.p[1] = hi;
    return r.v;
}

// One D-half-tile (4 fp32 rows) -> 8B of B k-slots (2x v_cvt_pkrtz).
__device__ __forceinline__ uint2 pack_half(f32x4 t) {
    uint2 r;
    r.x = __builtin_bit_cast(uint32_t, __builtin_amdgcn_cvt_pkrtz(t[0], t[1]));
    r.y = __builtin_bit_cast(uint32_t, __builtin_amdgcn_cvt_pkrtz(t[2], t[3]));
    return r;
}

// x[t] as B-fragment (k=0..3 live on lane-group 0 only).
__device__ __forceinline__ f16x8 bxpack(float4 xn, bool g0) {
    union { f16x8 v; uint32_t u[4]; } bx;
    bx.u[0] = g0 ? __builtin_bit_cast(uint32_t, __builtin_amdgcn_cvt_pkrtz(xn.x, xn.y)) : 0u;
    bx.u[1] = g0 ? __builtin_bit_cast(uint32_t, __builtin_amdgcn_cvt_pkrtz(xn.z, xn.w)) : 0u;
    bx.u[2] = 0u; bx.u[3] = 0u;
    return bx.v;
}

// R8 structure (best measured: 124us / 637 cy/step) with the recurrence chain
// de-lengthened:
//  (1) L1's two MFMAs now run in PARALLEL (p = Wih1*h0+b, q = Whh1*h1+0) and
//      are combined by a VALU add before tanh — removes one full dependent-MFMA
//      latency (~250 cy, fitted across R2/R5/R8/R11) from the critical wave.
//  (2) rtanh (1 trans) replaces exp2+rcp tanh (2 trans).
// Roles: wave0/1 = h0 rows 0-15/16-31; wave2/3 = h1 rows 0-15/16-31 (+head).
// Pipeline index i: A computes h0[i]; B computes h1[i-1]; head emits i-2.
__global__ __launch_bounds__(256, 2) void rnn2_quad3(
    const float* __restrict__ X,
    const float* __restrict__ W_ih0, const float* __restrict__ W_hh0,
    const float* __restrict__ b_ih0, const float* __restrict__ b_hh0,
    const float* __restrict__ W_ih1, const float* __restrict__ W_hh1,
    const float* __restrict__ b_ih1, const float* __restrict__ b_hh1,
    const float* __restrict__ W_ll, const float* __restrict__ b_ll,
    float* __restrict__ out)
{
    const int  tid  = threadIdx.x;
    const int  wid  = tid >> 6;        // 0,1 = L0 halves; 2,3 = L1 halves
    const int  half = wid & 1;         // 0: rows 0-15, 1: rows 16-31
    const int  isB  = wid >> 1;
    const int  l    = tid & 63;
    const int  c    = l & 15;          // batch col within tile
    const int  g    = l >> 4;          // k-group
    const bool g0   = (g == 0);
    const int  b    = blockIdx.x * 16 + c;
    const int  k0   = 4 * g;
    const int  ro   = half * 16;       // row offset of this wave's half

    __shared__ uint2 h0buf[2][2][64];  // [step parity][half][lane]
    __shared__ uint2 h1buf[2][2][64];

    // zero-init both parities (h0[-1]=h1[-1]=h1[-2]=0 fall out of this)
    h0buf[tid >> 7][(tid >> 6) & 1][tid & 63] = make_uint2(0u, 0u);
    h1buf[tid >> 7][(tid >> 6) & 1][tid & 63] = make_uint2(0u, 0u);
    __syncthreads();

    const float4 z4 = make_float4(0.f, 0.f, 0.f, 0.f);
    const f32x4  zf = {0.f, 0.f, 0.f, 0.f};

    if (isB == 0) {
        // ======== A-wave: layer 0, rows ro..ro+15 ========
        const float* wp = W_hh0 + (c + ro) * kH;
        const f16x8 Ahh = pack_frag(ld4(wp + k0), ld4(wp + 16 + k0));
        const f16x8 Aih = pack_frag(g0 ? ld4(W_ih0 + (c + ro) * kI) : z4, z4);
        f32x4 bias0;
#pragma unroll
        for (int r = 0; r < 4; ++r) bias0[r] = b_ih0[ro + k0 + r] + b_hh0[ro + k0 + r];

        uint2 myh = make_uint2(0u, 0u);   // own half of h0[i-1] (k-slots)
        f32x4 xc;                          // xc[i] = W_ih0·x[i] + b0 (this half)
        const float* xp = X + (size_t)b * (kT * kI);

        float4 xv0 = ld4(xp);
        float4 xv1 = ld4(xp + 1 * kI);
        float4 xv2 = ld4(xp + 2 * kI);
        float4 xcur[4];
#pragma unroll
        for (int u = 0; u < 4; ++u) xcur[u] = ld4(xp + (3 + u) * kI);
        xc = MFMA(Aih, bxpack(xv0, g0), bias0);

        auto stepA = [&](float4 xn, int i) {
            const int rp = (i - 1) & 1, wpar = i & 1;
            uint2 sib = h0buf[rp][half ^ 1][l];          // sibling half (ds_read)
            f32x4 xcn = MFMA(Aih, bxpack(xn, g0), bias0); // independent; covers read
            f16x8 Bh0 = half == 0 ? asm_frag(myh, sib) : asm_frag(sib, myh);
            f32x4 a = MFMA(Ahh, Bh0, xc);
            myh = pack_half(tanh4(a));
            h0buf[wpar][half][l] = myh;
            xc = xcn;
        };

        stepA(xv1, 0); bar_lds();   // i = 0
        stepA(xv2, 1); bar_lds();   // i = 1
        for (int tb = 0; tb < 128; ++tb) {
            const int i0 = 2 + tb * 4;
            float4 xnxt[4];
#pragma unroll
            for (int u = 0; u < 4; ++u) {
                int idx = i0 + 5 + u;
                idx = idx < kT ? idx : (kT - 1);
                xnxt[u] = ld4(xp + idx * kI);
            }
#pragma unroll
            for (int u = 0; u < 4; ++u) { stepA(xcur[u], i0 + u); bar_lds(); }
#pragma unroll
            for (int u = 0; u < 4; ++u) xcur[u] = xnxt[u];
        }
    } else {
        // ======== B-wave: layer 1 rows ro..ro+15 (+ head on half 0) ========
        const float* wp = W_ih1 + (c + ro) * kH;
        const f16x8 Aih1 = pack_frag(ld4(wp + k0), ld4(wp + 16 + k0));
        wp = W_hh1 + (c + ro) * kH;
        const f16x8 Ahh1 = pack_frag(ld4(wp + k0), ld4(wp + 16 + k0));
        const f16x8 All = (half == 0 && c < kO)
            ? pack_frag(ld4(W_ll + c * kH + k0), ld4(W_ll + c * kH + 16 + k0))
            : pack_frag(z4, z4);

        f32x4 bias1, biasll;
#pragma unroll
        for (int r = 0; r < 4; ++r) {
            bias1[r]  = b_ih1[ro + k0 + r] + b_hh1[ro + k0 + r];
            biasll[r] = g0 ? b_ll[r] : 0.f;
        }

        uint2 myh1 = make_uint2(0u, 0u);  // own half of h1[i-2]
        float* op = out + (size_t)b * (kT * kO);

        auto stepB = [&](int i, bool store) {
            const int rp = (i - 1) & 1, wpar = i & 1;
            uint2 h0lo = h0buf[rp][0][l];
            uint2 h0hi = h0buf[rp][1][l];
            uint2 sib1 = h1buf[rp][half ^ 1][l];
            f16x8 Bh0  = asm_frag(h0lo, h0hi);
            f16x8 Bh1v = half == 0 ? asm_frag(myh1, sib1) : asm_frag(sib1, myh1);
            f32x4 o;
            if (half == 0) o = MFMA(All, Bh1v, biasll);   // head, step i-2
            // PARALLEL MFMAs (independent), combined by VALU add:
            f32x4 p = MFMA(Aih1, Bh0, bias1);
            f32x4 q = MFMA(Ahh1, Bh1v, zf);
            myh1 = pack_half(tanh4(p + q));
            h1buf[wpar][half][l] = myh1;
            if (store && half == 0 && g0)
                *(float4*)(op + (size_t)(i - 2) * kO) = make_float4(o[0], o[1], o[2], o[3]);
        };

        bar_lds();                    // i = 0: buffers already zero; just sync
        stepB(1, false); bar_lds();   // i = 1: h1[0] from h0[0], h1[-1]=0
        for (int tb = 0; tb < 128; ++tb) {
            const int i0 = 2 + tb * 4;
#pragma unroll
            for (int u = 0; u < 4; ++u) { stepB(i0 + u, true); bar_lds(); }
        }
    }
}

extern "C" void kernel_launch(void* const* d_in, const int* in_sizes, int n_in,
                              void* d_out, int out_size, void* d_ws, size_t ws_size,
                              hipStream_t stream) {
    const float* X     = (const float*)d_in[0];
    const float* W_ih0 = (const float*)d_in[1];
    const float* W_hh0 = (const float*)d_in[2];
    const float* b_ih0 = (const float*)d_in[3];
    const float* b_hh0 = (const float*)d_in[4];
    const float* W_ih1 = (const float*)d_in[5];
    const float* W_hh1 = (const float*)d_in[6];
    const float* b_ih1 = (const float*)d_in[7];
    const float* b_hh1 = (const float*)d_in[8];
    const float* W_ll  = (const float*)d_in[9];
    const float* b_ll  = (const float*)d_in[10];
    float* out = (float*)d_out;

    rnn2_quad3<<<dim3(kB / 16), dim3(256), 0, stream>>>(
        X, W_ih0, W_hh0, b_ih0, b_hh0, W_ih1, W_hh1, b_ih1, b_hh1, W_ll, b_ll, out);
}